// Round 3
// baseline (1986.561 us; speedup 1.0000x reference)
//
#include <hip/hip_runtime.h>
#include <cfloat>
#include <climits>

#define TPB 256

// ---------------------------------------------------------------------------
// The reference harness recomputes the model with numpy in FLOAT32. The VQ
// argmin is taken over d = ||lat||^2 + ||e||^2 - 2*lat@emb.T evaluated in
// fp32 at magnitude ~0.6, so every d_k is quantized to a 6e-8 grid; ~1e-3 of
// rows are decided by a grid TIE resolved by first-index (np.argmin). To
// match, we must reproduce the fp32 op structure (k-sequential fma chains =
// BLAS micro-kernel order; uncontracted add/sub for the d assembly; numpy
// pairwise sums for the norms) and use first-index tie-breaks. Exact/f64
// computation provably CANNOT match (~18-35 row difference) — measured in
// rounds 1-2.
// ---------------------------------------------------------------------------

// Transposed-LDS GEMM tile. LDS layouts [k][row/col], stride 68 floats
// (64+4 pad, 272 B = 17*16 B keeps float4 alignment). 256 threads = 16x16;
// ty owns 4 rows, tx owns 4 cols; tx*4 offsets -> 2-way LDS aliasing (free).

template <int K>
__device__ __forceinline__ void stage_w64(float* __restrict__ sW,
                                          const float* __restrict__ Wc,
                                          int row_stride, int t) {
  constexpr int KQ = K / 4;
  for (int v = t; v < 64 * KQ; v += TPB) {
    const int c = v / KQ, k4 = v % KQ;
    const float4 wv =
        *reinterpret_cast<const float4*>(Wc + (size_t)c * row_stride + k4 * 4);
    float* dst = &sW[(k4 * 4) * 68 + c];
    dst[0] = wv.x; dst[68] = wv.y; dst[136] = wv.z; dst[204] = wv.w;
  }
}

// k-sequential single-accumulator fp32 fma chain — matches the BLAS
// micro-kernel accumulation order (rank-1 k-streaming, fma, acc from 0).
template <int K>
__device__ __forceinline__ void tile_fma(float (&acc)[4][4],
                                         const float* __restrict__ sIn,
                                         const float* __restrict__ sW,
                                         int ty4, int tx4) {
#pragma unroll 4
  for (int k = 0; k < K; ++k) {
    const float4 a = *reinterpret_cast<const float4*>(sIn + k * 68 + ty4);
    const float4 b = *reinterpret_cast<const float4*>(sW + k * 68 + tx4);
    const float av[4] = {a.x, a.y, a.z, a.w};
    const float bv[4] = {b.x, b.y, b.z, b.w};
#pragma unroll
    for (int i = 0; i < 4; ++i)
#pragma unroll
      for (int j = 0; j < 4; ++j) acc[i][j] = fmaf(av[i], bv[j], acc[i][j]);
  }
}

// ---------------------------------------------------------------------------
// Fused encoder: x[64 rows] -> relu(xW1^T+b1) -> relu(hW2^T+b2) -> lat
// Pure fp32, k-sequential — intended bitwise match with np's fp32 chain.
// ---------------------------------------------------------------------------
__global__ __launch_bounds__(TPB) void enc_kernel(
    const float* __restrict__ x, const float* __restrict__ W1,
    const float* __restrict__ b1, const float* __restrict__ W2,
    const float* __restrict__ b2, const float* __restrict__ W3,
    const float* __restrict__ b3, float* __restrict__ lat) {
  __shared__ float sA[128 * 68];   // x_t [128k][68r], later h2_t [128][68]
  __shared__ float sH1[256 * 68];  // h1_t [256][68]
  __shared__ float sW[128 * 68];   // weight chunk [k<=128][68c]
  const int t = threadIdx.x;
  const int ty4 = (t >> 4) * 4, tx4 = (t & 15) * 4;
  const int m0 = blockIdx.x * 64;

  for (int v = t; v < 64 * 32; v += TPB) {
    const int r = v >> 5, k4 = v & 31;
    const float4 xv =
        *reinterpret_cast<const float4*>(x + (size_t)(m0 + r) * 128 + k4 * 4);
    float* dst = &sA[(k4 * 4) * 68 + r];
    dst[0] = xv.x; dst[68] = xv.y; dst[136] = xv.z; dst[204] = xv.w;
  }
  __syncthreads();

  // ---- L1: out 256 (4 chunks of 64), K=128
  for (int oc = 0; oc < 4; ++oc) {
    if (oc) __syncthreads();
    stage_w64<128>(sW, W1 + (size_t)(oc * 64) * 128, 128, t);
    __syncthreads();
    float acc[4][4] = {};
    tile_fma<128>(acc, sA, sW, ty4, tx4);
#pragma unroll
    for (int j = 0; j < 4; ++j) {
      const float bj = b1[oc * 64 + tx4 + j];
#pragma unroll
      for (int i = 0; i < 4; ++i) {
        const float h = __fadd_rn(acc[i][j], bj);  // uncontracted add
        sH1[(oc * 64 + tx4 + j) * 68 + ty4 + i] = h > 0.f ? h : 0.f;
      }
    }
  }
  // ---- L2: out 128 (2 chunks), K=256 (2 halves of 128, k ascending)
  for (int oc = 0; oc < 2; ++oc) {
    float acc[4][4] = {};
    for (int kk = 0; kk < 2; ++kk) {
      __syncthreads();
      stage_w64<128>(sW, W2 + (size_t)(oc * 64) * 256 + kk * 128, 256, t);
      __syncthreads();
      tile_fma<128>(acc, sH1 + (kk * 128) * 68, sW, ty4, tx4);
    }
#pragma unroll
    for (int j = 0; j < 4; ++j) {
      const float bj = b2[oc * 64 + tx4 + j];
#pragma unroll
      for (int i = 0; i < 4; ++i) {
        const float h = __fadd_rn(acc[i][j], bj);
        sA[(oc * 64 + tx4 + j) * 68 + ty4 + i] = h > 0.f ? h : 0.f;
      }
    }
  }
  // ---- L3: out 64, K=128, no relu -> lat
  __syncthreads();
  stage_w64<128>(sW, W3, 128, t);
  __syncthreads();
  {
    float acc[4][4] = {};
    tile_fma<128>(acc, sA, sW, ty4, tx4);
#pragma unroll
    for (int i = 0; i < 4; ++i) {
      float4 o;
      o.x = __fadd_rn(acc[i][0], b3[tx4 + 0]);
      o.y = __fadd_rn(acc[i][1], b3[tx4 + 1]);
      o.z = __fadd_rn(acc[i][2], b3[tx4 + 2]);
      o.w = __fadd_rn(acc[i][3], b3[tx4 + 3]);
      *reinterpret_cast<float4*>(lat + (size_t)(m0 + ty4 + i) * 64 + tx4) = o;
    }
  }
}

// ---------------------------------------------------------------------------
// Codebook norms, numpy pairwise structure for n=64: 8 strided accumulators
// (j, j+8, ..., j+56 summed sequentially), then ((r0+r1)+(r2+r3))+((r4+r5)+
// (r6+r7)). All ops uncontracted fp32.
// ---------------------------------------------------------------------------
__global__ __launch_bounds__(TPB) void enorm_kernel(const float* __restrict__ emb,
                                                    float* __restrict__ En) {
  const int c = blockIdx.x * TPB + threadIdx.x;  // 8192
  const float* row = emb + (size_t)c * 64;
  float q[8];
#pragma unroll
  for (int j = 0; j < 8; ++j) q[j] = __fmul_rn(row[j], row[j]);
#pragma unroll
  for (int m = 1; m < 8; ++m)
#pragma unroll
    for (int j = 0; j < 8; ++j) {
      const float v = row[m * 8 + j];
      q[j] = __fadd_rn(q[j], __fmul_rn(v, v));
    }
  En[c] = __fadd_rn(
      __fadd_rn(__fadd_rn(q[0], q[1]), __fadd_rn(q[2], q[3])),
      __fadd_rn(__fadd_rn(q[4], q[5]), __fadd_rn(q[6], q[7])));
}

// ---------------------------------------------------------------------------
// VQ: replicate np-fp32 d_k = fl( fl(nl_r + ne_k) - fl(2*dot) ) and argmin
// with first-index ties. dot is a k-sequential fp32 fma chain (k=0..63),
// matching (2.0*lat)@emb.T via round(2x)=2*round(x). Fuses the per-row loss
// (d_min == ||q-lat||^2) and the full one_hot tile write.
// ---------------------------------------------------------------------------
__global__ __launch_bounds__(TPB) void vq_kernel(
    const float* __restrict__ lat, const float* __restrict__ emb,
    const float* __restrict__ En, int* __restrict__ inds,
    float* __restrict__ lossp, float* __restrict__ oh) {
  __shared__ float sL[64 * 68];    // lat_t [64d][68r]
  __shared__ float sE[64 * 132];   // emb_t chunk [64d][132c]
  __shared__ float sEn[128];
  __shared__ float snl[64];        // numpy-pairwise ||lat_r||^2
  __shared__ int ridx[64];
  __shared__ float lacc;
  const int t = threadIdx.x;
  const int tx = t & 15;
  const int ty4 = (t >> 4) * 4, tx4 = tx * 4;
  const int m0 = blockIdx.x * 64;

  for (int v = t; v < 64 * 16; v += TPB) {
    const int r = v >> 4, d4 = v & 15;
    const float4 lv =
        *reinterpret_cast<const float4*>(lat + (size_t)(m0 + r) * 64 + d4 * 4);
    float* dst = &sL[(d4 * 4) * 68 + r];
    dst[0] = lv.x; dst[68] = lv.y; dst[136] = lv.z; dst[204] = lv.w;
  }
  if (t == 0) lacc = 0.f;
  __syncthreads();
  if (t < 64) {  // numpy pairwise sum of lat_r^2 (n=64)
    float q[8];
#pragma unroll
    for (int j = 0; j < 8; ++j) {
      const float v = sL[j * 68 + t];
      q[j] = __fmul_rn(v, v);
    }
#pragma unroll
    for (int m = 1; m < 8; ++m)
#pragma unroll
      for (int j = 0; j < 8; ++j) {
        const float v = sL[(m * 8 + j) * 68 + t];
        q[j] = __fadd_rn(q[j], __fmul_rn(v, v));
      }
    snl[t] = __fadd_rn(
        __fadd_rn(__fadd_rn(q[0], q[1]), __fadd_rn(q[2], q[3])),
        __fadd_rn(__fadd_rn(q[4], q[5]), __fadd_rn(q[6], q[7])));
  }
  __syncthreads();
  const float nlv[4] = {snl[ty4 + 0], snl[ty4 + 1], snl[ty4 + 2],
                        snl[ty4 + 3]};

  float v1[4] = {FLT_MAX, FLT_MAX, FLT_MAX, FLT_MAX};
  int i1[4] = {INT_MAX, INT_MAX, INT_MAX, INT_MAX};

  for (int ch = 0; ch < 64; ++ch) {  // 8192 codes, chunks of 128
    const int c0 = ch * 128;
    __syncthreads();
    for (int v = t; v < 128 * 16; v += TPB) {
      const int c = v >> 4, d4 = v & 15;
      const float4 ev = *reinterpret_cast<const float4*>(
          emb + (size_t)(c0 + c) * 64 + d4 * 4);
      float* dst = &sE[(d4 * 4) * 132 + c];
      dst[0] = ev.x; dst[132] = ev.y; dst[264] = ev.z; dst[396] = ev.w;
    }
    if (t < 128) sEn[t] = En[c0 + t];
    __syncthreads();

    float acc[4][8] = {};
#pragma unroll 2
    for (int d = 0; d < 64; ++d) {  // k-sequential fma chain
      const float4 a = *reinterpret_cast<const float4*>(sL + d * 68 + ty4);
      const float4 b0 = *reinterpret_cast<const float4*>(sE + d * 132 + tx4);
      const float4 b1v =
          *reinterpret_cast<const float4*>(sE + d * 132 + 64 + tx4);
      const float av[4] = {a.x, a.y, a.z, a.w};
      const float bv[8] = {b0.x, b0.y, b0.z, b0.w, b1v.x, b1v.y, b1v.z, b1v.w};
#pragma unroll
      for (int i = 0; i < 4; ++i)
#pragma unroll
        for (int j = 0; j < 8; ++j) acc[i][j] = fmaf(av[i], bv[j], acc[i][j]);
    }
    // d = fl(fl(nl+ne) - fl(2*dot)); ascending code order + strict '<'
    // keeps the FIRST occurrence of the minimum (np.argmin tie semantics —
    // ties on the 6e-8 grid are common and decisive).
#pragma unroll
    for (int g = 0; g < 2; ++g)
#pragma unroll
      for (int j = 0; j < 4; ++j) {
        const int cl = g * 64 + tx4 + j;
        const float Ec = sEn[cl];
        const int c = c0 + cl;
#pragma unroll
        for (int i = 0; i < 4; ++i) {
          const float t1 = __fadd_rn(nlv[i], Ec);
          const float s =
              __fsub_rn(t1, __fmul_rn(2.0f, acc[i][g * 4 + j]));
          if (s < v1[i]) { v1[i] = s; i1[i] = c; }
        }
      }
  }

  // merge across the 16 lanes of each row group, (value, index) lexicographic
#pragma unroll
  for (int m = 8; m >= 1; m >>= 1) {
#pragma unroll
    for (int i = 0; i < 4; ++i) {
      const float ov = __shfl_xor(v1[i], m);
      const int oi = __shfl_xor(i1[i], m);
      if (ov < v1[i] || (ov == v1[i] && oi < i1[i])) {
        v1[i] = ov; i1[i] = oi;
      }
    }
  }
  if (tx == 0) {
#pragma unroll
    for (int i = 0; i < 4; ++i) {
      const int r = ty4 + i;
      ridx[r] = i1[i];
      inds[m0 + r] = i1[i];
      atomicAdd(&lacc, v1[i]);  // d_min == ||q-lat||^2 for this row
    }
  }
  __syncthreads();
  if (t == 0) lossp[blockIdx.x] = lacc;

  // one_hot tile: 64 rows x 2048 float4, coalesced
  for (int v = t; v < 64 * 2048; v += TPB) {
    const int r = v >> 11, c4 = v & 2047;
    const int bi = ridx[r];
    const bool hit = (bi >> 2) == c4;
    float4 o;
    o.x = (hit && (bi & 3) == 0) ? 1.f : 0.f;
    o.y = (hit && (bi & 3) == 1) ? 1.f : 0.f;
    o.z = (hit && (bi & 3) == 2) ? 1.f : 0.f;
    o.w = (hit && (bi & 3) == 3) ? 1.f : 0.f;
    *reinterpret_cast<float4*>(oh + (size_t)(m0 + r) * 8192 + c4 * 4) = o;
  }
}

// ---------------------------------------------------------------------------
// Decoder: q=emb[ind] -> relu -> relu -> mu, log_var. fp32 (2e-2 threshold).
// ---------------------------------------------------------------------------
__global__ __launch_bounds__(TPB) void dec_kernel(
    const float* __restrict__ emb, const int* __restrict__ inds,
    const float* __restrict__ W1, const float* __restrict__ b1,
    const float* __restrict__ W2, const float* __restrict__ b2,
    const float* __restrict__ Wmu, const float* __restrict__ bmu,
    const float* __restrict__ Wlv, const float* __restrict__ blv,
    float* __restrict__ xh, float* __restrict__ xv) {
  __shared__ float sQ[64 * 68];
  __shared__ float sH1[128 * 68];
  __shared__ float sH2[256 * 68];
  __shared__ float sW[128 * 68];
  const int t = threadIdx.x;
  const int ty4 = (t >> 4) * 4, tx4 = (t & 15) * 4;
  const int m0 = blockIdx.x * 64;

  for (int v = t; v < 64 * 16; v += TPB) {
    const int r = v >> 4, d4 = v & 15;
    const int id = inds[m0 + r];
    const float4 ev =
        *reinterpret_cast<const float4*>(emb + (size_t)id * 64 + d4 * 4);
    float* dst = &sQ[(d4 * 4) * 68 + r];
    dst[0] = ev.x; dst[68] = ev.y; dst[136] = ev.z; dst[204] = ev.w;
  }
  __syncthreads();

  for (int oc = 0; oc < 2; ++oc) {  // L1: out 128, K=64
    if (oc) __syncthreads();
    stage_w64<64>(sW, W1 + (size_t)(oc * 64) * 64, 64, t);
    __syncthreads();
    float acc[4][4] = {};
    tile_fma<64>(acc, sQ, sW, ty4, tx4);
#pragma unroll
    for (int j = 0; j < 4; ++j) {
      const float bj = b1[oc * 64 + tx4 + j];
#pragma unroll
      for (int i = 0; i < 4; ++i) {
        float h = acc[i][j] + bj;
        h = h > 0.f ? h : 0.f;
        sH1[(oc * 64 + tx4 + j) * 68 + ty4 + i] = h;
      }
    }
  }
  for (int oc = 0; oc < 4; ++oc) {  // L2: out 256, K=128
    __syncthreads();
    stage_w64<128>(sW, W2 + (size_t)(oc * 64) * 128, 128, t);
    __syncthreads();
    float acc[4][4] = {};
    tile_fma<128>(acc, sH1, sW, ty4, tx4);
#pragma unroll
    for (int j = 0; j < 4; ++j) {
      const float bj = b2[oc * 64 + tx4 + j];
#pragma unroll
      for (int i = 0; i < 4; ++i) {
        float h = acc[i][j] + bj;
        h = h > 0.f ? h : 0.f;
        sH2[(oc * 64 + tx4 + j) * 68 + ty4 + i] = h;
      }
    }
  }
  for (int head = 0; head < 2; ++head) {  // heads: out 128, K=256
    const float* W = head ? Wlv : Wmu;
    const float* b = head ? blv : bmu;
    float* o = head ? xv : xh;
    for (int oc = 0; oc < 2; ++oc) {
      float acc[4][4] = {};
      for (int kk = 0; kk < 2; ++kk) {
        __syncthreads();
        stage_w64<128>(sW, W + (size_t)(oc * 64) * 256 + kk * 128, 256, t);
        __syncthreads();
        tile_fma<128>(acc, sH2 + (kk * 128) * 68, sW, ty4, tx4);
      }
#pragma unroll
      for (int i = 0; i < 4; ++i) {
        float4 ov;
        ov.x = acc[i][0] + b[oc * 64 + tx4 + 0];
        ov.y = acc[i][1] + b[oc * 64 + tx4 + 1];
        ov.z = acc[i][2] + b[oc * 64 + tx4 + 2];
        ov.w = acc[i][3] + b[oc * 64 + tx4 + 3];
        *reinterpret_cast<float4*>(o + (size_t)(m0 + ty4 + i) * 128 + oc * 64 +
                                   tx4) = ov;
      }
    }
  }
}

// vq_loss = 2.25 * sum(d_min) / (N*LAT)
__global__ void fin_kernel(const float* __restrict__ lossp,
                           float* __restrict__ outp) {
  const int t = threadIdx.x;  // 64
  double s = 0.0;
  for (int i = t; i < 512; i += 64) s += (double)lossp[i];
#pragma unroll
  for (int m = 32; m >= 1; m >>= 1) s += __shfl_xor(s, m);
  if (t == 0) *outp = (float)(2.25 * s / (32768.0 * 64.0));
}

// ---------------------------------------------------------------------------
extern "C" void kernel_launch(void* const* d_in, const int* in_sizes, int n_in,
                              void* d_out, int out_size, void* d_ws,
                              size_t ws_size, hipStream_t stream) {
  const float* x = (const float*)d_in[0];
  const float* eW1 = (const float*)d_in[1];
  const float* eb1 = (const float*)d_in[2];
  const float* eW2 = (const float*)d_in[3];
  const float* eb2 = (const float*)d_in[4];
  const float* eW3 = (const float*)d_in[5];
  const float* eb3 = (const float*)d_in[6];
  const float* emb = (const float*)d_in[7];
  const float* dW1 = (const float*)d_in[8];
  const float* db1 = (const float*)d_in[9];
  const float* dW2 = (const float*)d_in[10];
  const float* db2 = (const float*)d_in[11];
  const float* dWmu = (const float*)d_in[12];
  const float* dbmu = (const float*)d_in[13];
  const float* dWlv = (const float*)d_in[14];
  const float* dblv = (const float*)d_in[15];

  float* out = (float*)d_out;
  float* xhat = out;                 // [32768,128]
  float* xvar = out + 4194304;       // [32768,128]
  float* oh = out + 8388608;         // [32768,8192]
  float* lossout = out + 276824064;  // scalar

  float* lat = (float*)d_ws;         // 2,097,152 floats
  float* En = lat + 2097152;         // 8,192
  float* lossp = En + 8192;          // 512
  int* inds = (int*)(lossp + 512);   // 32,768 ints

  enorm_kernel<<<32, TPB, 0, stream>>>(emb, En);
  enc_kernel<<<512, TPB, 0, stream>>>(x, eW1, eb1, eW2, eb2, eW3, eb3, lat);
  vq_kernel<<<512, TPB, 0, stream>>>(lat, emb, En, inds, lossp, oh);
  dec_kernel<<<512, TPB, 0, stream>>>(emb, inds, dW1, db1, dW2, db2, dWmu,
                                      dbmu, dWlv, dblv, xhat, xvar);
  fin_kernel<<<1, 64, 0, stream>>>(lossp, lossout);
}